// Round 5
// baseline (547.094 us; speedup 1.0000x reference)
//
#include <hip/hip_runtime.h>
#include <hip/hip_bf16.h>
#include <cmath>

#define ALPHA 1.702f
#define LIMIT 7.0f

constexpr int B = 2, S = 1024, H = 768, E = 8, I = 768;
constexpr int T = B * S;          // 2048 tokens
constexpr int TWO_I = 2 * I;      // 1536
constexpr int CAP = T;            // per-expert row capacity
constexpr int NT1 = I / 64;       // 12 n-tiles (gemm1)
constexpr int NT2 = H / 64;       // 12 n-tiles (gemm2)
constexpr int MT = CAP / 128;     // 16 m-tiles

constexpr int GRID = 512;         // 2 blocks/CU, co-resident by construction

constexpr int RTR_BLKS = 64;
constexpr int WGU_TILES = E * (TWO_I / 64) * (H / 64);  // 2304
constexpr int WD_TILES  = E * (H / 64) * (H / 64);      // 1152
constexpr int P0_ITEMS = RTR_BLKS + WGU_TILES;          // 2368 (= 296 chunks of 8)
constexpr int G1_BLKS = MT * E * NT1;                   // 1536
constexpr int P1_ITEMS = G1_BLKS + WD_TILES;            // 2688 (= 336 chunks of 8)
constexpr int G2_BLKS = MT * E * NT2;                   // 1536

typedef __attribute__((ext_vector_type(8))) short short8;
typedef __attribute__((ext_vector_type(4))) float floatx4;

__device__ __forceinline__ unsigned short f2bf(float v) {
  __hip_bfloat16 h = __float2bfloat16(v);
  return *reinterpret_cast<unsigned short*>(&h);
}

__device__ __forceinline__ void g2l16(const void* g, void* l) {
  __builtin_amdgcn_global_load_lds(
      (const __attribute__((address_space(1))) void*)g,
      (__attribute__((address_space(3))) void*)l, 16, 0, 0);
}

struct G1Smem {
  short As[2][128 * 64];  // 32 KB
  short Bg[2][64 * 64];   // 16 KB
  short Bu[2][64 * 64];   // 16 KB
  int tok[128];
};
struct G2Smem {
  short As[2][128 * 64];
  short Bs[2][64 * 64];
  int tok[128];
  float wts[128];
};
struct RtrSmem {
  int cnt_s[E];
  int base_s[E];
  int tok_e[E][64];
  float wv_e[E][64];
};
union SmemAll {
  G1Smem g1;
  G2Smem g2;
  float tile[64][65];
  RtrSmem rtr;
};  // 66048 B -> 2 blocks/CU (132 KB < 160 KB)

// ---------------------------------------------------------------------------
// Manual grid barrier (all GRID blocks co-resident). Release: per-thread
// stores drained by __syncthreads, then agent-scope fence (L2 writeback) +
// device-scope arrive. Acquire: spin on agent-scope load, fence (L2 inv).
// ---------------------------------------------------------------------------
__device__ __forceinline__ void grid_bar(int* cnt, int tid) {
  __syncthreads();
  if (tid == 0) {
    __threadfence();
    __hip_atomic_fetch_add(cnt, 1, __ATOMIC_ACQ_REL, __HIP_MEMORY_SCOPE_AGENT);
    while (__hip_atomic_load(cnt, __ATOMIC_ACQUIRE,
                             __HIP_MEMORY_SCOPE_AGENT) < GRID) {
      __builtin_amdgcn_s_sleep(2);
    }
    __threadfence();
  }
  __syncthreads();
}

// ---------------------------------------------------------------------------
// 64x64 fp32->bf16 transpose tile via LDS (R1-proven body).
// ---------------------------------------------------------------------------
__device__ __forceinline__ void transpose_tile(
    const float* __restrict__ in, unsigned short* __restrict__ outw,
    int N, int n0, int k0, float (*tile)[65], int tid) {
  constexpr int K = 768;
  int jr = tid & 15, r0 = tid >> 4;
#pragma unroll
  for (int p = 0; p < 4; p++) {
    int k = r0 + p * 16;
    float4 v = *(const float4*)(in + (size_t)(k0 + k) * N + n0 + jr * 4);
    tile[k][jr * 4 + 0] = v.x;
    tile[k][jr * 4 + 1] = v.y;
    tile[k][jr * 4 + 2] = v.z;
    tile[k][jr * 4 + 3] = v.w;
  }
  __syncthreads();
#pragma unroll
  for (int p = 0; p < 4; p++) {
    int n = r0 + p * 16;
    ushort4 o;
    o.x = f2bf(tile[jr * 4 + 0][n]);
    o.y = f2bf(tile[jr * 4 + 1][n]);
    o.z = f2bf(tile[jr * 4 + 2][n]);
    o.w = f2bf(tile[jr * 4 + 3][n]);
    *(ushort4*)(outw + (size_t)(n0 + n) * K + k0 + jr * 4) = o;
  }
}

// ---------------------------------------------------------------------------
// Router item: 32 tokens (4 waves x 8). Logits+top2+softmax, xb cast,
// out zero, block-aggregated assignment (1 global atomic per expert).
// ---------------------------------------------------------------------------
__device__ __forceinline__ void router_item(
    int rbid, int tid, RtrSmem& rs, const float* __restrict__ x,
    const float* __restrict__ Wr, const float* __restrict__ br,
    unsigned short* __restrict__ xb, float* __restrict__ out,
    int* __restrict__ e_cnt, int* __restrict__ row_token,
    float* __restrict__ row_w) {
  if (tid < E) rs.cnt_s[tid] = 0;
  __syncthreads();

  int wave = tid >> 6;
  int lane = tid & 63;

  for (int tt = 0; tt < 8; tt++) {
    int t = rbid * 32 + wave * 8 + tt;
    const float* xr = x + (size_t)t * H;

    float4 z4 = {0.f, 0.f, 0.f, 0.f};
#pragma unroll
    for (int j = 0; j < 3; j++)
      *(float4*)(out + (size_t)t * H + (size_t)(j * 64 + lane) * 4) = z4;

    float acc[E];
#pragma unroll
    for (int e = 0; e < E; e++) acc[e] = 0.0f;

#pragma unroll
    for (int it = 0; it < 3; it++) {
      int h4 = it * 64 + lane;
      float4 xv = *(const float4*)(xr + (size_t)h4 * 4);
      ushort4 xo;
      xo.x = f2bf(xv.x);
      xo.y = f2bf(xv.y);
      xo.z = f2bf(xv.z);
      xo.w = f2bf(xv.w);
      *(ushort4*)(xb + (size_t)t * H + (size_t)h4 * 4) = xo;
      const float* wrow = Wr + (size_t)h4 * 4 * E;
      float xs[4] = {xv.x, xv.y, xv.z, xv.w};
#pragma unroll
      for (int j = 0; j < 4; j++)
#pragma unroll
        for (int e = 0; e < E; e++) acc[e] += xs[j] * wrow[j * E + e];
    }
#pragma unroll
    for (int e = 0; e < E; e++) {
      float v = acc[e];
      for (int off = 32; off > 0; off >>= 1) v += __shfl_down(v, off, 64);
      acc[e] = v;
    }
    if (lane == 0) {
      float logits[E];
#pragma unroll
      for (int e = 0; e < E; e++) logits[e] = acc[e] + br[e];
      int i0 = 0;
      float v0 = logits[0];
#pragma unroll
      for (int e = 1; e < E; e++)
        if (logits[e] > v0) { v0 = logits[e]; i0 = e; }
      int i1 = -1;
      float v1 = -INFINITY;
#pragma unroll
      for (int e = 0; e < E; e++) {
        if (e == i0) continue;
        if (logits[e] > v1) { v1 = logits[e]; i1 = e; }
      }
      float s1 = __expf(v1 - v0);
      float denom = 1.0f + s1;
      int p0 = atomicAdd(&rs.cnt_s[i0], 1);
      rs.tok_e[i0][p0] = t;
      rs.wv_e[i0][p0] = 1.0f / denom;
      int p1 = atomicAdd(&rs.cnt_s[i1], 1);
      rs.tok_e[i1][p1] = t;
      rs.wv_e[i1][p1] = s1 / denom;
    }
  }
  __syncthreads();
  if (tid < E) rs.base_s[tid] = atomicAdd(&e_cnt[tid], rs.cnt_s[tid]);
  __syncthreads();
#pragma unroll
  for (int e = 0; e < E; e++) {
    int c = rs.cnt_s[e], b0 = rs.base_s[e];
    for (int j = tid; j < c; j += 256) {
      row_token[e * CAP + b0 + j] = rs.tok_e[e][j];
      row_w[e * CAP + b0 + j] = rs.wv_e[e][j];
    }
  }
}

// ---------------------------------------------------------------------------
// GEMM1 item: 128m x 64n gate+up, K=768, BK=64, XOR swizzle, dbuf, vmcnt(8).
// (byte-identical math to the R1/R3 proven version)
// ---------------------------------------------------------------------------
__device__ __forceinline__ void gemm1_item(
    int item, int tid, G1Smem& sm, const unsigned short* __restrict__ xb,
    const unsigned short* __restrict__ Wgt, const float* __restrict__ bgu,
    const int* __restrict__ e_cnt, const int* __restrict__ row_token,
    unsigned short* __restrict__ act) {
  int g = item % (E * NT1);
  int mt = item / (E * NT1);
  int e = g / NT1;
  int n0 = (g % NT1) * 64;
  int cnt = e_cnt[e];
  int m0 = mt * 128;
  if (m0 >= cnt) return;
  int start = e * CAP;
  const unsigned short* Wg = Wgt + (size_t)e * TWO_I * H;
  const float* bias = bgu + (size_t)e * TWO_I;

  if (tid < 128) {
    int m = m0 + tid;
    sm.tok[tid] = row_token[start + ((m < cnt) ? m : (cnt - 1))];
  }
  __syncthreads();

  int lane = tid & 63;
  int wave = tid >> 6;
  int quad = lane >> 4;
  int lrow = lane & 15;
  int wm = (wave >> 1) * 64;
  int wn = (wave & 1) * 32;

  const unsigned short* gA[4];
  int oA[4];
#pragma unroll
  for (int r = 0; r < 4; r++) {
    int s = (wave * 4 + r) * 64 + lane;
    int row = s >> 3;
    int gg = (s & 7) ^ (row & 7);
    gA[r] = xb + (size_t)sm.tok[row] * H + gg * 8;
    oA[r] = (wave * 4 + r) * 64 * 8;
  }
  const unsigned short *gBg[2], *gBu[2];
  int oB[2];
#pragma unroll
  for (int r = 0; r < 2; r++) {
    int s = (wave * 2 + r) * 64 + lane;
    int row = s >> 3;
    int gg = (s & 7) ^ (row & 7);
    gBg[r] = Wg + (size_t)(n0 + row) * H + gg * 8;
    gBu[r] = gBg[r] + (size_t)I * H;
    oB[r] = (wave * 2 + r) * 64 * 8;
  }

  float bgv[2], buv[2];
#pragma unroll
  for (int tj = 0; tj < 2; tj++) {
    int ncol = n0 + wn + tj * 16 + lrow;
    bgv[tj] = bias[ncol];
    buv[tj] = bias[I + ncol];
  }

  floatx4 accg[4][2], accu[4][2];
#pragma unroll
  for (int i = 0; i < 4; i++)
#pragma unroll
    for (int j = 0; j < 2; j++) {
      accg[i][j] = floatx4{0.f, 0.f, 0.f, 0.f};
      accu[i][j] = floatx4{0.f, 0.f, 0.f, 0.f};
    }

  __syncthreads();

#pragma unroll
  for (int r = 0; r < 4; r++) g2l16(gA[r], &sm.As[0][oA[r]]);
#pragma unroll
  for (int r = 0; r < 2; r++) {
    g2l16(gBg[r], &sm.Bg[0][oB[r]]);
    g2l16(gBu[r], &sm.Bu[0][oB[r]]);
  }

  constexpr int NK = H / 64;  // 12
  for (int i = 0; i < NK; i++) {
    int cb = i & 1;
    if (i + 1 < NK) {
      int nb = cb ^ 1;
      int k1 = (i + 1) * 64;
#pragma unroll
      for (int r = 0; r < 4; r++) g2l16(gA[r] + k1, &sm.As[nb][oA[r]]);
#pragma unroll
      for (int r = 0; r < 2; r++) {
        g2l16(gBg[r] + k1, &sm.Bg[nb][oB[r]]);
        g2l16(gBu[r] + k1, &sm.Bu[nb][oB[r]]);
      }
      asm volatile("s_waitcnt vmcnt(8)" ::: "memory");
    } else {
      asm volatile("s_waitcnt vmcnt(0)" ::: "memory");
    }
    __builtin_amdgcn_s_barrier();

#pragma unroll
    for (int ks = 0; ks < 2; ks++) {
      int c = ks * 4 + quad;
      short8 a[4], bg[2], bu[2];
#pragma unroll
      for (int ti = 0; ti < 4; ti++) {
        int r = wm + ti * 16 + lrow;
        a[ti] = *(const short8*)(&sm.As[cb][(r * 8 + (c ^ (r & 7))) * 8]);
      }
#pragma unroll
      for (int tj = 0; tj < 2; tj++) {
        int r = wn + tj * 16 + lrow;
        bg[tj] = *(const short8*)(&sm.Bg[cb][(r * 8 + (c ^ (r & 7))) * 8]);
        bu[tj] = *(const short8*)(&sm.Bu[cb][(r * 8 + (c ^ (r & 7))) * 8]);
      }
#pragma unroll
      for (int ti = 0; ti < 4; ti++)
#pragma unroll
        for (int tj = 0; tj < 2; tj++) {
          accg[ti][tj] = __builtin_amdgcn_mfma_f32_16x16x32_bf16(
              a[ti], bg[tj], accg[ti][tj], 0, 0, 0);
          accu[ti][tj] = __builtin_amdgcn_mfma_f32_16x16x32_bf16(
              a[ti], bu[tj], accu[ti][tj], 0, 0, 0);
        }
    }
    __builtin_amdgcn_s_barrier();
  }

#pragma unroll
  for (int ti = 0; ti < 4; ti++) {
#pragma unroll
    for (int tj = 0; tj < 2; tj++) {
      int ncol = n0 + wn + tj * 16 + lrow;
#pragma unroll
      for (int r = 0; r < 4; r++) {
        int m = m0 + wm + ti * 16 + quad * 4 + r;
        if (m < cnt) {
          float gg = accg[ti][tj][r] + bgv[tj];
          float u = accu[ti][tj][r] + buv[tj];
          gg = fminf(gg, LIMIT);
          u = fmaxf(fminf(u, LIMIT), -LIMIT);
          float glu = gg / (1.0f + __expf(-ALPHA * gg));
          act[(size_t)(start + m) * I + ncol] = f2bf((u + 1.0f) * glu);
        }
      }
    }
  }
}

// ---------------------------------------------------------------------------
// GEMM2 item: 128m x 64n, K=768, dbuf, vmcnt(6), weighted atomic scatter.
// ---------------------------------------------------------------------------
__device__ __forceinline__ void gemm2_item(
    int item, int tid, G2Smem& sm, const unsigned short* __restrict__ act,
    const unsigned short* __restrict__ Wdt, const float* __restrict__ bd,
    const int* __restrict__ e_cnt, const int* __restrict__ row_token,
    const float* __restrict__ row_w, float* __restrict__ out) {
  int g = item % (E * NT2);
  int mt = item / (E * NT2);
  int e = g / NT2;
  int n0 = (g % NT2) * 64;
  int cnt = e_cnt[e];
  int m0 = mt * 128;
  if (m0 >= cnt) return;
  int start = e * CAP;
  const unsigned short* Wd = Wdt + (size_t)e * H * I;
  const float* bias = bd + (size_t)e * H;

  if (tid < 128) {
    int m = m0 + tid;
    int mm = (m < cnt) ? m : (cnt - 1);
    sm.tok[tid] = row_token[start + mm];
    sm.wts[tid] = row_w[start + mm];
  }
  __syncthreads();

  int lane = tid & 63;
  int wave = tid >> 6;
  int quad = lane >> 4;
  int lrow = lane & 15;
  int wm = (wave >> 1) * 64;
  int wn = (wave & 1) * 32;

  const unsigned short* gA[4];
  int oA[4];
#pragma unroll
  for (int r = 0; r < 4; r++) {
    int s = (wave * 4 + r) * 64 + lane;
    int row = s >> 3;
    int gg = (s & 7) ^ (row & 7);
    int gm = m0 + row;
    int mm = (gm < cnt) ? gm : (cnt - 1);
    gA[r] = act + (size_t)(start + mm) * I + gg * 8;
    oA[r] = (wave * 4 + r) * 64 * 8;
  }
  const unsigned short* gB[2];
  int oB[2];
#pragma unroll
  for (int r = 0; r < 2; r++) {
    int s = (wave * 2 + r) * 64 + lane;
    int row = s >> 3;
    int gg = (s & 7) ^ (row & 7);
    gB[r] = Wd + (size_t)(n0 + row) * I + gg * 8;
    oB[r] = (wave * 2 + r) * 64 * 8;
  }

  float bdv[2];
#pragma unroll
  for (int tj = 0; tj < 2; tj++) bdv[tj] = bias[n0 + wn + tj * 16 + lrow];

  floatx4 acc[4][2];
#pragma unroll
  for (int i = 0; i < 4; i++)
#pragma unroll
    for (int j = 0; j < 2; j++) acc[i][j] = floatx4{0.f, 0.f, 0.f, 0.f};

  __syncthreads();

#pragma unroll
  for (int r = 0; r < 4; r++) g2l16(gA[r], &sm.As[0][oA[r]]);
#pragma unroll
  for (int r = 0; r < 2; r++) g2l16(gB[r], &sm.Bs[0][oB[r]]);

  constexpr int NK = I / 64;  // 12
  for (int i = 0; i < NK; i++) {
    int cb = i & 1;
    if (i + 1 < NK) {
      int nb = cb ^ 1;
      int k1 = (i + 1) * 64;
#pragma unroll
      for (int r = 0; r < 4; r++) g2l16(gA[r] + k1, &sm.As[nb][oA[r]]);
#pragma unroll
      for (int r = 0; r < 2; r++) g2l16(gB[r] + k1, &sm.Bs[nb][oB[r]]);
      asm volatile("s_waitcnt vmcnt(6)" ::: "memory");
    } else {
      asm volatile("s_waitcnt vmcnt(0)" ::: "memory");
    }
    __builtin_amdgcn_s_barrier();

#pragma unroll
    for (int ks = 0; ks < 2; ks++) {
      int c = ks * 4 + quad;
      short8 a[4], b[2];
#pragma unroll
      for (int ti = 0; ti < 4; ti++) {
        int r = wm + ti * 16 + lrow;
        a[ti] = *(const short8*)(&sm.As[cb][(r * 8 + (c ^ (r & 7))) * 8]);
      }
#pragma unroll
      for (int tj = 0; tj < 2; tj++) {
        int r = wn + tj * 16 + lrow;
        b[tj] = *(const short8*)(&sm.Bs[cb][(r * 8 + (c ^ (r & 7))) * 8]);
      }
#pragma unroll
      for (int ti = 0; ti < 4; ti++)
#pragma unroll
        for (int tj = 0; tj < 2; tj++)
          acc[ti][tj] = __builtin_amdgcn_mfma_f32_16x16x32_bf16(
              a[ti], b[tj], acc[ti][tj], 0, 0, 0);
    }
    __builtin_amdgcn_s_barrier();
  }

#pragma unroll
  for (int ti = 0; ti < 4; ti++) {
#pragma unroll
    for (int tj = 0; tj < 2; tj++) {
      int ncol = n0 + wn + tj * 16 + lrow;
#pragma unroll
      for (int r = 0; r < 4; r++) {
        int ml = wm + ti * 16 + quad * 4 + r;
        int m = m0 + ml;
        if (m < cnt) {
          atomicAdd(&out[(size_t)sm.tok[ml] * H + ncol],
                    sm.wts[ml] * (acc[ti][tj][r] + bdv[tj]));
        }
      }
    }
  }
}

// ---------------------------------------------------------------------------
// fused_all: whole pipeline, ONE persistent kernel, manual grid barriers.
//   phase 0: router + Wgu transpose   (chunk-interleaved 1:36)
//   phase 1: gemm1 + Wd transpose     (chunk-interleaved 4:3 -> memory work
//                                      overlaps MFMA work within each round)
//   phase 2: gemm2
// Item remap is in chunks of 8 so item%8 == bid%8 (stride 512 = 0 mod 8)
// -> the gemm B-slab -> XCD L2 affinity is preserved.
// ---------------------------------------------------------------------------
__global__ __launch_bounds__(256, 2) void fused_all(
    const float* __restrict__ x, const float* __restrict__ Wr,
    const float* __restrict__ br, const float* __restrict__ Wgu,
    const float* __restrict__ Wd, const float* __restrict__ bgu,
    const float* __restrict__ bd, unsigned short* __restrict__ Wgt,
    unsigned short* __restrict__ Wdt, unsigned short* __restrict__ xb,
    unsigned short* __restrict__ act, float* __restrict__ out,
    int* __restrict__ e_cnt, int* __restrict__ row_token,
    float* __restrict__ row_w, int* __restrict__ bar) {
  __shared__ __align__(16) SmemAll sm;
  int tid = threadIdx.x;
  int bid = blockIdx.x;

  // ---------------- phase 0: router + Wgu transpose ----------------
  for (int i = bid; i < P0_ITEMS; i += GRID) {
    __syncthreads();  // protect union-aliased LDS across items
    int c = i >> 3, o = i & 7;
    int g = c / 37, r = c % 37;
    if (r == 0) {
      router_item(g * 8 + o, tid, sm.rtr, x, Wr, br, xb, out, e_cnt,
                  row_token, row_w);
    } else {
      int q = (g * 36 + (r - 1)) * 8 + o;
      int e = q / 288, rem = q % 288;
      int n0 = (rem % 24) * 64;
      int k0 = (rem / 24) * 64;
      transpose_tile(Wgu + (size_t)e * H * TWO_I, Wgt + (size_t)e * TWO_I * H,
                     TWO_I, n0, k0, sm.tile, tid);
    }
  }
  grid_bar(&bar[0], tid);

  // ---------------- phase 1: gemm1 + Wd transpose ----------------
  for (int i = bid; i < P1_ITEMS; i += GRID) {
    __syncthreads();
    int c = i >> 3, o = i & 7;
    int g = c / 7, r = c % 7;
    if (r < 4) {
      gemm1_item((g * 4 + r) * 8 + o, tid, sm.g1, xb, Wgt, bgu, e_cnt,
                 row_token, act);
    } else {
      int q = (g * 3 + (r - 4)) * 8 + o;
      int e = q / 144, rem = q % 144;
      int n0 = (rem % 12) * 64;
      int k0 = (rem / 12) * 64;
      transpose_tile(Wd + (size_t)e * H * I, Wdt + (size_t)e * H * I, H, n0,
                     k0, sm.tile, tid);
    }
  }
  grid_bar(&bar[1], tid);

  // ---------------- phase 2: gemm2 ----------------
  for (int i = bid; i < G2_BLKS; i += GRID) {
    __syncthreads();
    gemm2_item(i, tid, sm.g2, act, Wdt, bd, e_cnt, row_token, row_w, out);
  }
}

// ---------------------------------------------------------------------------
extern "C" void kernel_launch(void* const* d_in, const int* in_sizes, int n_in,
                              void* d_out, int out_size, void* d_ws,
                              size_t ws_size, hipStream_t stream) {
  const float* x   = (const float*)d_in[0];
  const float* Wr  = (const float*)d_in[1];
  const float* br  = (const float*)d_in[2];
  const float* Wgu = (const float*)d_in[3];
  const float* bgu = (const float*)d_in[4];
  const float* Wd  = (const float*)d_in[5];
  const float* bd  = (const float*)d_in[6];
  float* out = (float*)d_out;

  char* w = (char*)d_ws;
  int* e_cnt = (int*)w;       w += 16 * sizeof(int);  // [0..7]=e_cnt, [8..9]=bar
  int* bar = e_cnt + 8;
  int* row_token = (int*)w;   w += (size_t)E * CAP * sizeof(int);
  float* row_w = (float*)w;   w += (size_t)E * CAP * sizeof(float);
  unsigned short* xb  = (unsigned short*)w; w += (size_t)T * H * 2;         // 3.1 MB
  unsigned short* Wgt = (unsigned short*)w; w += (size_t)E * TWO_I * H * 2; // 18.9 MB
  unsigned short* Wdt = (unsigned short*)w; w += (size_t)E * H * I * 2;     // 9.4 MB
  unsigned short* act = (unsigned short*)w; w += (size_t)E * CAP * I * 2;   // 25.2 MB

  hipMemsetAsync(e_cnt, 0, 16 * sizeof(int), stream);
  fused_all<<<GRID, 256, 0, stream>>>(
      x, Wr, br, Wgu, Wd, bgu, bd, Wgt, Wdt, xb, act, out, e_cnt, row_token,
      row_w, bar);
}

// Round 7
// 171.909 us; speedup vs baseline: 3.1825x; 3.1825x over previous
//
#include <hip/hip_runtime.h>
#include <hip/hip_bf16.h>
#include <cmath>

#define ALPHA 1.702f
#define LIMIT 7.0f

constexpr int B = 2, S = 1024, H = 768, E = 8, I = 768;
constexpr int T = B * S;          // 2048 tokens
constexpr int TWO_I = 2 * I;      // 1536
constexpr int CAP = T;            // per-expert row capacity
constexpr int NT1 = I / 64;       // 12 n-tiles (gemm1)
constexpr int NT2 = H / 64;       // 12 n-tiles (gemm2)
constexpr int MT64 = CAP / 64;    // 32 m-tiles (M=64)

constexpr int RTR_BLKS = 64;
constexpr int WGU_TILES = E * (TWO_I / 64) * (H / 64);  // 2304
constexpr int WD_TILES  = E * (H / 64) * (H / 64);      // 1152
constexpr int PRE_BLKS = RTR_BLKS + WGU_TILES;          // 2368
constexpr int G1_BLKS = MT64 * E * NT1;                 // 3072
constexpr int K1_BLKS = G1_BLKS + WD_TILES;             // 4224
constexpr int G2_BLKS = MT64 * E * NT2;                 // 3072

typedef __attribute__((ext_vector_type(8))) short short8;
typedef __attribute__((ext_vector_type(4))) float floatx4;

__device__ __forceinline__ unsigned short f2bf(float v) {
  __hip_bfloat16 h = __float2bfloat16(v);
  return *reinterpret_cast<unsigned short*>(&h);
}

// async global->LDS, 16B per lane. LDS dst is wave-uniform base + lane*16.
__device__ __forceinline__ void g2l16(const void* g, void* l) {
  __builtin_amdgcn_global_load_lds(
      (const __attribute__((address_space(1))) void*)g,
      (__attribute__((address_space(3))) void*)l, 16, 0, 0);
}

// 64x64 fp32->bf16 transpose tile via LDS (R1-proven body).
__device__ __forceinline__ void transpose_tile(
    const float* __restrict__ in, unsigned short* __restrict__ outw,
    int N, int n0, int k0, float (*tile)[65], int tid) {
  constexpr int K = 768;
  int jr = tid & 15, r0 = tid >> 4;
#pragma unroll
  for (int p = 0; p < 4; p++) {
    int k = r0 + p * 16;
    float4 v = *(const float4*)(in + (size_t)(k0 + k) * N + n0 + jr * 4);
    tile[k][jr * 4 + 0] = v.x;
    tile[k][jr * 4 + 1] = v.y;
    tile[k][jr * 4 + 2] = v.z;
    tile[k][jr * 4 + 3] = v.w;
  }
  __syncthreads();
#pragma unroll
  for (int p = 0; p < 4; p++) {
    int n = r0 + p * 16;
    ushort4 o;
    o.x = f2bf(tile[jr * 4 + 0][n]);
    o.y = f2bf(tile[jr * 4 + 1][n]);
    o.z = f2bf(tile[jr * 4 + 2][n]);
    o.w = f2bf(tile[jr * 4 + 3][n]);
    *(ushort4*)(outw + (size_t)(n0 + n) * K + k0 + jr * 4) = o;
  }
}

// ---------------------------------------------------------------------------
// K0: router (+assignment, xb cast, out zero) and Wgu transpose in ONE launch.
// (byte-identical to the R3 162.8 µs version)
// ---------------------------------------------------------------------------
__global__ __launch_bounds__(256) void pre_router_wgu(
    const float* __restrict__ x, const float* __restrict__ Wr,
    const float* __restrict__ br, const float* __restrict__ Wgu,
    unsigned short* __restrict__ Wgt, unsigned short* __restrict__ xb,
    float* __restrict__ out, int* __restrict__ e_cnt,
    int* __restrict__ row_token, float* __restrict__ row_w) {
  int bid = blockIdx.x;
  int tid = threadIdx.x;

  if (bid < RTR_BLKS) {
    __shared__ int cnt_s[E];
    __shared__ int base_s[E];
    __shared__ int tok_e[E][64];
    __shared__ float wv_e[E][64];

    if (tid < E) cnt_s[tid] = 0;
    __syncthreads();

    int wave = tid >> 6;
    int lane = tid & 63;

    for (int tt = 0; tt < 8; tt++) {
      int t = bid * 32 + wave * 8 + tt;
      const float* xr = x + (size_t)t * H;

      float4 z4 = {0.f, 0.f, 0.f, 0.f};
#pragma unroll
      for (int j = 0; j < 3; j++)
        *(float4*)(out + (size_t)t * H + (size_t)(j * 64 + lane) * 4) = z4;

      float acc[E];
#pragma unroll
      for (int e = 0; e < E; e++) acc[e] = 0.0f;

#pragma unroll
      for (int it = 0; it < 3; it++) {
        int h4 = it * 64 + lane;
        float4 xv = *(const float4*)(xr + (size_t)h4 * 4);
        ushort4 xo;
        xo.x = f2bf(xv.x);
        xo.y = f2bf(xv.y);
        xo.z = f2bf(xv.z);
        xo.w = f2bf(xv.w);
        *(ushort4*)(xb + (size_t)t * H + (size_t)h4 * 4) = xo;
        const float* wrow = Wr + (size_t)h4 * 4 * E;
        float xs[4] = {xv.x, xv.y, xv.z, xv.w};
#pragma unroll
        for (int j = 0; j < 4; j++)
#pragma unroll
          for (int e = 0; e < E; e++) acc[e] += xs[j] * wrow[j * E + e];
      }
#pragma unroll
      for (int e = 0; e < E; e++) {
        float v = acc[e];
        for (int off = 32; off > 0; off >>= 1) v += __shfl_down(v, off, 64);
        acc[e] = v;
      }
      if (lane == 0) {
        float logits[E];
#pragma unroll
        for (int e = 0; e < E; e++) logits[e] = acc[e] + br[e];
        int i0 = 0;
        float v0 = logits[0];
#pragma unroll
        for (int e = 1; e < E; e++)
          if (logits[e] > v0) { v0 = logits[e]; i0 = e; }
        int i1 = -1;
        float v1 = -INFINITY;
#pragma unroll
        for (int e = 0; e < E; e++) {
          if (e == i0) continue;
          if (logits[e] > v1) { v1 = logits[e]; i1 = e; }
        }
        float s1 = __expf(v1 - v0);
        float denom = 1.0f + s1;
        int p0 = atomicAdd(&cnt_s[i0], 1);
        tok_e[i0][p0] = t;
        wv_e[i0][p0] = 1.0f / denom;
        int p1 = atomicAdd(&cnt_s[i1], 1);
        tok_e[i1][p1] = t;
        wv_e[i1][p1] = s1 / denom;
      }
    }
    __syncthreads();
    if (tid < E) base_s[tid] = atomicAdd(&e_cnt[tid], cnt_s[tid]);
    __syncthreads();
#pragma unroll
    for (int e = 0; e < E; e++) {
      int c = cnt_s[e], b0 = base_s[e];
      for (int j = tid; j < c; j += 256) {
        row_token[e * CAP + b0 + j] = tok_e[e][j];
        row_w[e * CAP + b0 + j] = wv_e[e][j];
      }
    }
    return;
  }

  // Wgu transpose tiles
  __shared__ float tile[64][65];
  int q = bid - RTR_BLKS;
  int e = q / 288, rem = q % 288;
  int n0 = (rem % 24) * 64;
  int k0 = (rem / 24) * 64;
  transpose_tile(Wgu + (size_t)e * H * TWO_I, Wgt + (size_t)e * TWO_I * H,
                 TWO_I, n0, k0, tile, tid);
}

// ---------------------------------------------------------------------------
// K1: gemm1 at M=64 (R1's proven 2-stage BK=64 dbuf template, parameter
// change only: 48.3 KB LDS -> 3 blocks/CU = 12 waves/CU for latency hiding)
// + Wd transpose blocks appended (R3-proven overlap).
// Staging per wave per stage: 2 A + 2 Bg + 2 Bu = 6 DMAs -> vmcnt(6).
// Same (s&7)^(row&7) swizzle and read formula as R1.
// ---------------------------------------------------------------------------
struct G1Smem {
  short As[2][64 * 64];  // 16 KB
  short Bg[2][64 * 64];  // 16 KB
  short Bu[2][64 * 64];  // 16 KB
  int tok[64];
};
struct TSmem {
  float tile[64][65];
};

__global__ __launch_bounds__(256) void gemm_gu_wdT(
    const unsigned short* __restrict__ xb, const unsigned short* __restrict__ Wgt,
    const float* __restrict__ bgu, const int* __restrict__ e_cnt,
    const int* __restrict__ row_token, unsigned short* __restrict__ act,
    const float* __restrict__ Wd, unsigned short* __restrict__ Wdt) {
  __shared__ __align__(16) char smem_raw[sizeof(G1Smem) > sizeof(TSmem)
                                             ? sizeof(G1Smem)
                                             : sizeof(TSmem)];
  int bid = blockIdx.x;
  int tid = threadIdx.x;

  if (bid >= G1_BLKS) {
    TSmem* ts = (TSmem*)smem_raw;
    int q = bid - G1_BLKS;
    int e = q / 144, rem = q % 144;
    int n0 = (rem % 12) * 64;
    int k0 = (rem / 12) * 64;
    transpose_tile(Wd + (size_t)e * H * I, Wdt + (size_t)e * H * I,
                   H, n0, k0, ts->tile, tid);
    return;
  }

  G1Smem* sm = (G1Smem*)smem_raw;
  int g = bid % (E * NT1);       // (e*12 + n), fixed XCD = g%8
  int mt = bid / (E * NT1);      // 0..31
  int e = g / NT1;
  int n0 = (g % NT1) * 64;
  int cnt = e_cnt[e];
  int m0 = mt * 64;
  if (m0 >= cnt) return;
  int start = e * CAP;
  const unsigned short* Wg = Wgt + (size_t)e * TWO_I * H;  // [f][h]
  const float* bias = bgu + (size_t)e * TWO_I;

  if (tid < 64) {
    int m = m0 + tid;
    sm->tok[tid] = row_token[start + ((m < cnt) ? m : (cnt - 1))];
  }
  __syncthreads();

  int lane = tid & 63;
  int wave = tid >> 6;
  int quad = lane >> 4;
  int lrow = lane & 15;
  int wm = (wave >> 1) * 32;
  int wn = (wave & 1) * 32;

  // A staging: 64x64 tile = 8 KB = 512 16B-units = 2 g2l16/thread.
  const unsigned short* gA[2];
  int oA[2];
#pragma unroll
  for (int r = 0; r < 2; r++) {
    int s = (wave * 2 + r) * 64 + lane;  // 0..511
    int row = s >> 3;                    // 0..63
    int gg = (s & 7) ^ (row & 7);
    gA[r] = xb + (size_t)sm->tok[row] * H + gg * 8;
    oA[r] = (wave * 2 + r) * 64 * 8;
  }
  // B staging: same geometry for Bg and Bu.
  const unsigned short *gBg[2], *gBu[2];
  int oB[2];
#pragma unroll
  for (int r = 0; r < 2; r++) {
    int s = (wave * 2 + r) * 64 + lane;
    int row = s >> 3;
    int gg = (s & 7) ^ (row & 7);
    gBg[r] = Wg + (size_t)(n0 + row) * H + gg * 8;
    gBu[r] = gBg[r] + (size_t)I * H;
    oB[r] = (wave * 2 + r) * 64 * 8;
  }

  float bgv[2], buv[2];
#pragma unroll
  for (int tj = 0; tj < 2; tj++) {
    int ncol = n0 + wn + tj * 16 + lrow;
    bgv[tj] = bias[ncol];
    buv[tj] = bias[I + ncol];
  }

  floatx4 accg[2][2], accu[2][2];
#pragma unroll
  for (int i = 0; i < 2; i++)
#pragma unroll
    for (int j = 0; j < 2; j++) {
      accg[i][j] = floatx4{0.f, 0.f, 0.f, 0.f};
      accu[i][j] = floatx4{0.f, 0.f, 0.f, 0.f};
    }

  __syncthreads();  // drain so in-loop vmcnt sees only staging DMAs

#pragma unroll
  for (int r = 0; r < 2; r++) g2l16(gA[r], &sm->As[0][oA[r]]);
#pragma unroll
  for (int r = 0; r < 2; r++) {
    g2l16(gBg[r], &sm->Bg[0][oB[r]]);
    g2l16(gBu[r], &sm->Bu[0][oB[r]]);
  }

  constexpr int NK = H / 64;  // 12
  for (int i = 0; i < NK; i++) {
    int cb = i & 1;
    if (i + 1 < NK) {
      int nb = cb ^ 1;
      int k1 = (i + 1) * 64;
#pragma unroll
      for (int r = 0; r < 2; r++) g2l16(gA[r] + k1, &sm->As[nb][oA[r]]);
#pragma unroll
      for (int r = 0; r < 2; r++) {
        g2l16(gBg[r] + k1, &sm->Bg[nb][oB[r]]);
        g2l16(gBu[r] + k1, &sm->Bu[nb][oB[r]]);
      }
      asm volatile("s_waitcnt vmcnt(6)" ::: "memory");
    } else {
      asm volatile("s_waitcnt vmcnt(0)" ::: "memory");
    }
    __builtin_amdgcn_s_barrier();

#pragma unroll
    for (int ks = 0; ks < 2; ks++) {
      int c = ks * 4 + quad;
      short8 a[2], bg[2], bu[2];
#pragma unroll
      for (int ti = 0; ti < 2; ti++) {
        int r = wm + ti * 16 + lrow;
        a[ti] = *(const short8*)(&sm->As[cb][(r * 8 + (c ^ (r & 7))) * 8]);
      }
#pragma unroll
      for (int tj = 0; tj < 2; tj++) {
        int r = wn + tj * 16 + lrow;
        bg[tj] = *(const short8*)(&sm->Bg[cb][(r * 8 + (c ^ (r & 7))) * 8]);
        bu[tj] = *(const short8*)(&sm->Bu[cb][(r * 8 + (c ^ (r & 7))) * 8]);
      }
#pragma unroll
      for (int ti = 0; ti < 2; ti++)
#pragma unroll
        for (int tj = 0; tj < 2; tj++) {
          accg[ti][tj] = __builtin_amdgcn_mfma_f32_16x16x32_bf16(
              a[ti], bg[tj], accg[ti][tj], 0, 0, 0);
          accu[ti][tj] = __builtin_amdgcn_mfma_f32_16x16x32_bf16(
              a[ti], bu[tj], accu[ti][tj], 0, 0, 0);
        }
    }
    __builtin_amdgcn_s_barrier();  // reads of cb done before refill
  }

#pragma unroll
  for (int ti = 0; ti < 2; ti++) {
#pragma unroll
    for (int tj = 0; tj < 2; tj++) {
      int ncol = n0 + wn + tj * 16 + lrow;
#pragma unroll
      for (int r = 0; r < 4; r++) {
        int m = m0 + wm + ti * 16 + quad * 4 + r;
        if (m < cnt) {
          float gg = accg[ti][tj][r] + bgv[tj];
          float u = accu[ti][tj][r] + buv[tj];
          gg = fminf(gg, LIMIT);
          u = fmaxf(fminf(u, LIMIT), -LIMIT);
          float glu = gg / (1.0f + __expf(-ALPHA * gg));
          act[(size_t)(start + m) * I + ncol] = f2bf((u + 1.0f) * glu);
        }
      }
    }
  }
}

// ---------------------------------------------------------------------------
// GEMM2 at M=64: 32.5 KB LDS -> 4 blocks/CU = 16 waves/CU. 2-stage BK=64,
// vmcnt(4) (2 A + 2 B per wave per stage). Weighted atomic scatter epilogue.
// ---------------------------------------------------------------------------
__global__ __launch_bounds__(256) void gemm_down_mfma(
    const unsigned short* __restrict__ act, const unsigned short* __restrict__ Wdt,
    const float* __restrict__ bd, const int* __restrict__ e_cnt,
    const int* __restrict__ row_token, const float* __restrict__ row_w,
    float* __restrict__ out) {
  int bid = blockIdx.x;
  int g = bid % (E * NT2);
  int mt = bid / (E * NT2);
  int e = g / NT2;
  int n0 = (g % NT2) * 64;
  int cnt = e_cnt[e];
  int m0 = mt * 64;
  if (m0 >= cnt) return;
  int start = e * CAP;
  const unsigned short* Wd = Wdt + (size_t)e * H * I;  // [h][i]
  const float* bias = bd + (size_t)e * H;

  __shared__ short As[2][64 * 64];  // 16 KB
  __shared__ short Bs[2][64 * 64];  // 16 KB
  __shared__ int tok[64];
  __shared__ float wts[64];

  int tid = threadIdx.x;
  if (tid < 64) {
    int m = m0 + tid;
    int mm = (m < cnt) ? m : (cnt - 1);
    tok[tid] = row_token[start + mm];
    wts[tid] = row_w[start + mm];
  }
  __syncthreads();

  int lane = tid & 63;
  int wave = tid >> 6;
  int quad = lane >> 4;
  int lrow = lane & 15;
  int wm = (wave >> 1) * 32;
  int wn = (wave & 1) * 32;

  const unsigned short* gA[2];
  int oA[2];
#pragma unroll
  for (int r = 0; r < 2; r++) {
    int s = (wave * 2 + r) * 64 + lane;
    int row = s >> 3;
    int gg = (s & 7) ^ (row & 7);
    int gm = m0 + row;
    int mm = (gm < cnt) ? gm : (cnt - 1);
    gA[r] = act + (size_t)(start + mm) * I + gg * 8;
    oA[r] = (wave * 2 + r) * 64 * 8;
  }
  const unsigned short* gB[2];
  int oB[2];
#pragma unroll
  for (int r = 0; r < 2; r++) {
    int s = (wave * 2 + r) * 64 + lane;
    int row = s >> 3;
    int gg = (s & 7) ^ (row & 7);
    gB[r] = Wd + (size_t)(n0 + row) * I + gg * 8;
    oB[r] = (wave * 2 + r) * 64 * 8;
  }

  float bdv[2];
#pragma unroll
  for (int tj = 0; tj < 2; tj++) bdv[tj] = bias[n0 + wn + tj * 16 + lrow];

  floatx4 acc[2][2];
#pragma unroll
  for (int i = 0; i < 2; i++)
#pragma unroll
    for (int j = 0; j < 2; j++) acc[i][j] = floatx4{0.f, 0.f, 0.f, 0.f};

  __syncthreads();  // drain; in-loop vmcnt sees only the 4 staging DMAs

#pragma unroll
  for (int r = 0; r < 2; r++) g2l16(gA[r], &As[0][oA[r]]);
#pragma unroll
  for (int r = 0; r < 2; r++) g2l16(gB[r], &Bs[0][oB[r]]);

  constexpr int NK = I / 64;  // 12
  for (int i = 0; i < NK; i++) {
    int cb = i & 1;
    if (i + 1 < NK) {
      int nb = cb ^ 1;
      int k1 = (i + 1) * 64;
#pragma unroll
      for (int r = 0; r < 2; r++) g2l16(gA[r] + k1, &As[nb][oA[r]]);
#pragma unroll
      for (int r = 0; r < 2; r++) g2l16(gB[r] + k1, &Bs[nb][oB[r]]);
      asm volatile("s_waitcnt vmcnt(4)" ::: "memory");
    } else {
      asm volatile("s_waitcnt vmcnt(0)" ::: "memory");
    }
    __builtin_amdgcn_s_barrier();

#pragma unroll
    for (int ks = 0; ks < 2; ks++) {
      int c = ks * 4 + quad;
      short8 a[2], b[2];
#pragma unroll
      for (int ti = 0; ti < 2; ti++) {
        int r = wm + ti * 16 + lrow;
        a[ti] = *(const short8*)(&As[cb][(r * 8 + (c ^ (r & 7))) * 8]);
      }
#pragma unroll
      for (int tj = 0; tj < 2; tj++) {
        int r = wn + tj * 16 + lrow;
        b[tj] = *(const short8*)(&Bs[cb][(r * 8 + (c ^ (r & 7))) * 8]);
      }
#pragma unroll
      for (int ti = 0; ti < 2; ti++)
#pragma unroll
        for (int tj = 0; tj < 2; tj++)
          acc[ti][tj] = __builtin_amdgcn_mfma_f32_16x16x32_bf16(
              a[ti], b[tj], acc[ti][tj], 0, 0, 0);
    }
    __builtin_amdgcn_s_barrier();
  }

#pragma unroll
  for (int ti = 0; ti < 2; ti++) {
#pragma unroll
    for (int tj = 0; tj < 2; tj++) {
      int ncol = n0 + wn + tj * 16 + lrow;
#pragma unroll
      for (int r = 0; r < 4; r++) {
        int ml = wm + ti * 16 + quad * 4 + r;
        int m = m0 + ml;
        if (m < cnt) {
          atomicAdd(&out[(size_t)tok[ml] * H + ncol],
                    wts[ml] * (acc[ti][tj][r] + bdv[tj]));
        }
      }
    }
  }
}

// ---------------------------------------------------------------------------
extern "C" void kernel_launch(void* const* d_in, const int* in_sizes, int n_in,
                              void* d_out, int out_size, void* d_ws,
                              size_t ws_size, hipStream_t stream) {
  const float* x   = (const float*)d_in[0];
  const float* Wr  = (const float*)d_in[1];
  const float* br  = (const float*)d_in[2];
  const float* Wgu = (const float*)d_in[3];
  const float* bgu = (const float*)d_in[4];
  const float* Wd  = (const float*)d_in[5];
  const float* bd  = (const float*)d_in[6];
  float* out = (float*)d_out;

  char* w = (char*)d_ws;
  int* e_cnt = (int*)w;       w += 16 * sizeof(int);
  int* row_token = (int*)w;   w += (size_t)E * CAP * sizeof(int);
  float* row_w = (float*)w;   w += (size_t)E * CAP * sizeof(float);
  unsigned short* xb  = (unsigned short*)w; w += (size_t)T * H * 2;         // 3.1 MB
  unsigned short* Wgt = (unsigned short*)w; w += (size_t)E * TWO_I * H * 2; // 18.9 MB
  unsigned short* Wdt = (unsigned short*)w; w += (size_t)E * H * I * 2;     // 9.4 MB
  unsigned short* act = (unsigned short*)w; w += (size_t)E * CAP * I * 2;   // 25.2 MB

  hipMemsetAsync(e_cnt, 0, 16 * sizeof(int), stream);
  pre_router_wgu<<<PRE_BLKS, 256, 0, stream>>>(
      x, Wr, br, Wgu, Wgt, xb, out, e_cnt, row_token, row_w);
  gemm_gu_wdT<<<K1_BLKS, 256, 0, stream>>>(
      xb, Wgt, bgu, e_cnt, row_token, act, Wd, Wdt);
  gemm_down_mfma<<<G2_BLKS, 256, 0, stream>>>(
      act, Wdt, bd, e_cnt, row_token, row_w, out);
}

// Round 8
// 159.937 us; speedup vs baseline: 3.4207x; 1.0749x over previous
//
#include <hip/hip_runtime.h>
#include <hip/hip_bf16.h>
#include <cmath>

#define ALPHA 1.702f
#define LIMIT 7.0f

constexpr int B = 2, S = 1024, H = 768, E = 8, I = 768;
constexpr int T = B * S;          // 2048 tokens
constexpr int TWO_I = 2 * I;      // 1536
constexpr int CAP = T;            // per-expert row capacity
constexpr int NT1 = I / 64;       // 12 n-tiles (gemm1)
constexpr int NT2 = H / 64;       // 12 n-tiles (gemm2)
constexpr int MT = CAP / 128;     // 16 m-tiles

constexpr int RTR_BLKS = 64;
constexpr int WGU_TILES = E * (TWO_I / 64) * (H / 64);  // 2304
constexpr int WD_TILES  = E * (H / 64) * (H / 64);      // 1152
constexpr int PRE_BLKS = RTR_BLKS + WGU_TILES;          // 2368
constexpr int G1_BLKS = MT * E * NT1;                   // 1536
constexpr int K1_BLKS = G1_BLKS + WD_TILES;             // 2688
constexpr int G2_BLKS = MT * E * NT2;                   // 1536
constexpr int RED_BLKS = (T * H / 4) / 256;             // 1536 (one float4/thread)

typedef __attribute__((ext_vector_type(8))) short short8;
typedef __attribute__((ext_vector_type(4))) float floatx4;

__device__ __forceinline__ unsigned short f2bf(float v) {
  __hip_bfloat16 h = __float2bfloat16(v);
  return *reinterpret_cast<unsigned short*>(&h);
}

// async global->LDS, 16B per lane. LDS dst is wave-uniform base + lane*16.
__device__ __forceinline__ void g2l16(const void* g, void* l) {
  __builtin_amdgcn_global_load_lds(
      (const __attribute__((address_space(1))) void*)g,
      (__attribute__((address_space(3))) void*)l, 16, 0, 0);
}

// 64x64 fp32->bf16 transpose tile via LDS (R1-proven body).
__device__ __forceinline__ void transpose_tile(
    const float* __restrict__ in, unsigned short* __restrict__ outw,
    int N, int n0, int k0, float (*tile)[65], int tid) {
  constexpr int K = 768;
  int jr = tid & 15, r0 = tid >> 4;
#pragma unroll
  for (int p = 0; p < 4; p++) {
    int k = r0 + p * 16;
    float4 v = *(const float4*)(in + (size_t)(k0 + k) * N + n0 + jr * 4);
    tile[k][jr * 4 + 0] = v.x;
    tile[k][jr * 4 + 1] = v.y;
    tile[k][jr * 4 + 2] = v.z;
    tile[k][jr * 4 + 3] = v.w;
  }
  __syncthreads();
#pragma unroll
  for (int p = 0; p < 4; p++) {
    int n = r0 + p * 16;
    ushort4 o;
    o.x = f2bf(tile[jr * 4 + 0][n]);
    o.y = f2bf(tile[jr * 4 + 1][n]);
    o.z = f2bf(tile[jr * 4 + 2][n]);
    o.w = f2bf(tile[jr * 4 + 3][n]);
    *(ushort4*)(outw + (size_t)(n0 + n) * K + k0 + jr * 4) = o;
  }
}

// ---------------------------------------------------------------------------
// K0: router (+assignment, xb cast) and Wgu transpose in ONE launch.
// row_token now encodes t*2+slot (slot 0 = top1, 1 = top2) so gemm2 can
// scatter into a dense [t][slot][H] buffer with plain stores (no atomics).
// out zero-fill removed: the reduce kernel fully overwrites out.
// ---------------------------------------------------------------------------
__global__ __launch_bounds__(256) void pre_router_wgu(
    const float* __restrict__ x, const float* __restrict__ Wr,
    const float* __restrict__ br, const float* __restrict__ Wgu,
    unsigned short* __restrict__ Wgt, unsigned short* __restrict__ xb,
    int* __restrict__ e_cnt, int* __restrict__ row_token,
    float* __restrict__ row_w) {
  int bid = blockIdx.x;
  int tid = threadIdx.x;

  if (bid < RTR_BLKS) {
    __shared__ int cnt_s[E];
    __shared__ int base_s[E];
    __shared__ int tok_e[E][64];
    __shared__ float wv_e[E][64];

    if (tid < E) cnt_s[tid] = 0;
    __syncthreads();

    int wave = tid >> 6;
    int lane = tid & 63;

    for (int tt = 0; tt < 8; tt++) {
      int t = bid * 32 + wave * 8 + tt;
      const float* xr = x + (size_t)t * H;

      float acc[E];
#pragma unroll
      for (int e = 0; e < E; e++) acc[e] = 0.0f;

#pragma unroll
      for (int it = 0; it < 3; it++) {
        int h4 = it * 64 + lane;
        float4 xv = *(const float4*)(xr + (size_t)h4 * 4);
        ushort4 xo;
        xo.x = f2bf(xv.x);
        xo.y = f2bf(xv.y);
        xo.z = f2bf(xv.z);
        xo.w = f2bf(xv.w);
        *(ushort4*)(xb + (size_t)t * H + (size_t)h4 * 4) = xo;
        const float* wrow = Wr + (size_t)h4 * 4 * E;
        float xs[4] = {xv.x, xv.y, xv.z, xv.w};
#pragma unroll
        for (int j = 0; j < 4; j++)
#pragma unroll
          for (int e = 0; e < E; e++) acc[e] += xs[j] * wrow[j * E + e];
      }
#pragma unroll
      for (int e = 0; e < E; e++) {
        float v = acc[e];
        for (int off = 32; off > 0; off >>= 1) v += __shfl_down(v, off, 64);
        acc[e] = v;
      }
      if (lane == 0) {
        float logits[E];
#pragma unroll
        for (int e = 0; e < E; e++) logits[e] = acc[e] + br[e];
        int i0 = 0;
        float v0 = logits[0];
#pragma unroll
        for (int e = 1; e < E; e++)
          if (logits[e] > v0) { v0 = logits[e]; i0 = e; }
        int i1 = -1;
        float v1 = -INFINITY;
#pragma unroll
        for (int e = 0; e < E; e++) {
          if (e == i0) continue;
          if (logits[e] > v1) { v1 = logits[e]; i1 = e; }
        }
        float s1 = __expf(v1 - v0);
        float denom = 1.0f + s1;
        int p0 = atomicAdd(&cnt_s[i0], 1);
        tok_e[i0][p0] = t * 2 + 0;       // slot 0
        wv_e[i0][p0] = 1.0f / denom;
        int p1 = atomicAdd(&cnt_s[i1], 1);
        tok_e[i1][p1] = t * 2 + 1;       // slot 1
        wv_e[i1][p1] = s1 / denom;
      }
    }
    __syncthreads();
    if (tid < E) base_s[tid] = atomicAdd(&e_cnt[tid], cnt_s[tid]);
    __syncthreads();
#pragma unroll
    for (int e = 0; e < E; e++) {
      int c = cnt_s[e], b0 = base_s[e];
      for (int j = tid; j < c; j += 256) {
        row_token[e * CAP + b0 + j] = tok_e[e][j];
        row_w[e * CAP + b0 + j] = wv_e[e][j];
      }
    }
    return;
  }

  // Wgu transpose tiles
  __shared__ float tile[64][65];
  int q = bid - RTR_BLKS;
  int e = q / 288, rem = q % 288;
  int n0 = (rem % 24) * 64;
  int k0 = (rem / 24) * 64;
  transpose_tile(Wgu + (size_t)e * H * TWO_I, Wgt + (size_t)e * TWO_I * H,
                 TWO_I, n0, k0, tile, tid);
}

// ---------------------------------------------------------------------------
// K1: gemm1 (bid < 1536, R3-proven 128m x 64n 2-stage BK=64 template, same
// bid%8 XCD affinity) + 1152 Wd-transpose blocks appended (R3-proven
// overlap). Only change vs R3: token index is tok>>1 (slot-encoded).
// ---------------------------------------------------------------------------
struct G1Smem {
  short As[2][128 * 64];
  short Bg[2][64 * 64];
  short Bu[2][64 * 64];
  int tok[128];
};
struct TSmem {
  float tile[64][65];
};

__global__ __launch_bounds__(256) void gemm_gu_wdT(
    const unsigned short* __restrict__ xb, const unsigned short* __restrict__ Wgt,
    const float* __restrict__ bgu, const int* __restrict__ e_cnt,
    const int* __restrict__ row_token, unsigned short* __restrict__ act,
    const float* __restrict__ Wd, unsigned short* __restrict__ Wdt) {
  __shared__ __align__(16) char smem_raw[sizeof(G1Smem)];
  int bid = blockIdx.x;
  int tid = threadIdx.x;

  if (bid >= G1_BLKS) {
    // ------------------- Wd transpose tile -------------------
    TSmem* ts = (TSmem*)smem_raw;
    int q = bid - G1_BLKS;
    int e = q / 144, rem = q % 144;
    int n0 = (rem % 12) * 64;
    int k0 = (rem / 12) * 64;
    transpose_tile(Wd + (size_t)e * H * I, Wdt + (size_t)e * H * I,
                   H, n0, k0, ts->tile, tid);
    return;
  }

  // ------------------- gemm1 (R3 structure) -------------------
  G1Smem* sm = (G1Smem*)smem_raw;
  int g = bid % (E * NT1);       // (e*12 + n), fixed XCD = g%8
  int mt = bid / (E * NT1);      // m-tile
  int e = g / NT1;
  int n0 = (g % NT1) * 64;
  int cnt = e_cnt[e];
  int m0 = mt * 128;
  if (m0 >= cnt) return;
  int start = e * CAP;
  const unsigned short* Wg = Wgt + (size_t)e * TWO_I * H;  // [f][h]
  const float* bias = bgu + (size_t)e * TWO_I;

  if (tid < 128) {
    int m = m0 + tid;
    sm->tok[tid] = row_token[start + ((m < cnt) ? m : (cnt - 1))];
  }
  __syncthreads();

  int lane = tid & 63;
  int wave = tid >> 6;
  int quad = lane >> 4;
  int lrow = lane & 15;
  int wm = (wave >> 1) * 64;
  int wn = (wave & 1) * 32;

  const unsigned short* gA[4];
  int oA[4];
#pragma unroll
  for (int r = 0; r < 4; r++) {
    int s = (wave * 4 + r) * 64 + lane;
    int row = s >> 3;
    int gg = (s & 7) ^ (row & 7);
    gA[r] = xb + (size_t)(sm->tok[row] >> 1) * H + gg * 8;
    oA[r] = (wave * 4 + r) * 64 * 8;
  }
  const unsigned short *gBg[2], *gBu[2];
  int oB[2];
#pragma unroll
  for (int r = 0; r < 2; r++) {
    int s = (wave * 2 + r) * 64 + lane;
    int row = s >> 3;
    int gg = (s & 7) ^ (row & 7);
    gBg[r] = Wg + (size_t)(n0 + row) * H + gg * 8;
    gBu[r] = gBg[r] + (size_t)I * H;
    oB[r] = (wave * 2 + r) * 64 * 8;
  }

  float bgv[2], buv[2];
#pragma unroll
  for (int tj = 0; tj < 2; tj++) {
    int ncol = n0 + wn + tj * 16 + lrow;
    bgv[tj] = bias[ncol];
    buv[tj] = bias[I + ncol];
  }

  floatx4 accg[4][2], accu[4][2];
#pragma unroll
  for (int i = 0; i < 4; i++)
#pragma unroll
    for (int j = 0; j < 2; j++) {
      accg[i][j] = floatx4{0.f, 0.f, 0.f, 0.f};
      accu[i][j] = floatx4{0.f, 0.f, 0.f, 0.f};
    }

  __syncthreads();  // drain so in-loop vmcnt sees only staging DMAs

#pragma unroll
  for (int r = 0; r < 4; r++) g2l16(gA[r], &sm->As[0][oA[r]]);
#pragma unroll
  for (int r = 0; r < 2; r++) {
    g2l16(gBg[r], &sm->Bg[0][oB[r]]);
    g2l16(gBu[r], &sm->Bu[0][oB[r]]);
  }

  constexpr int NK = H / 64;  // 12
  for (int i = 0; i < NK; i++) {
    int cb = i & 1;
    if (i + 1 < NK) {
      int nb = cb ^ 1;
      int k1 = (i + 1) * 64;
#pragma unroll
      for (int r = 0; r < 4; r++) g2l16(gA[r] + k1, &sm->As[nb][oA[r]]);
#pragma unroll
      for (int r = 0; r < 2; r++) {
        g2l16(gBg[r] + k1, &sm->Bg[nb][oB[r]]);
        g2l16(gBu[r] + k1, &sm->Bu[nb][oB[r]]);
      }
      asm volatile("s_waitcnt vmcnt(8)" ::: "memory");
    } else {
      asm volatile("s_waitcnt vmcnt(0)" ::: "memory");
    }
    __builtin_amdgcn_s_barrier();

#pragma unroll
    for (int ks = 0; ks < 2; ks++) {
      int c = ks * 4 + quad;
      short8 a[4], bg[2], bu[2];
#pragma unroll
      for (int ti = 0; ti < 4; ti++) {
        int r = wm + ti * 16 + lrow;
        a[ti] = *(const short8*)(&sm->As[cb][(r * 8 + (c ^ (r & 7))) * 8]);
      }
#pragma unroll
      for (int tj = 0; tj < 2; tj++) {
        int r = wn + tj * 16 + lrow;
        bg[tj] = *(const short8*)(&sm->Bg[cb][(r * 8 + (c ^ (r & 7))) * 8]);
        bu[tj] = *(const short8*)(&sm->Bu[cb][(r * 8 + (c ^ (r & 7))) * 8]);
      }
#pragma unroll
      for (int ti = 0; ti < 4; ti++)
#pragma unroll
        for (int tj = 0; tj < 2; tj++) {
          accg[ti][tj] = __builtin_amdgcn_mfma_f32_16x16x32_bf16(
              a[ti], bg[tj], accg[ti][tj], 0, 0, 0);
          accu[ti][tj] = __builtin_amdgcn_mfma_f32_16x16x32_bf16(
              a[ti], bu[tj], accu[ti][tj], 0, 0, 0);
        }
    }
    __builtin_amdgcn_s_barrier();  // reads of cb done before refill
  }

#pragma unroll
  for (int ti = 0; ti < 4; ti++) {
#pragma unroll
    for (int tj = 0; tj < 2; tj++) {
      int ncol = n0 + wn + tj * 16 + lrow;
#pragma unroll
      for (int r = 0; r < 4; r++) {
        int m = m0 + wm + ti * 16 + quad * 4 + r;
        if (m < cnt) {
          float gg = accg[ti][tj][r] + bgv[tj];
          float u = accu[ti][tj][r] + buv[tj];
          gg = fminf(gg, LIMIT);
          u = fmaxf(fminf(u, LIMIT), -LIMIT);
          float glu = gg / (1.0f + __expf(-ALPHA * gg));
          act[(size_t)(start + m) * I + ncol] = f2bf((u + 1.0f) * glu);
        }
      }
    }
  }
}

// ---------------------------------------------------------------------------
// GEMM2: down = act @ Wd[e] (+bd), weighted; scatter via PLAIN STORES into
// dense down[t][slot][H] (each (t,slot,h) written exactly once — the t*2+slot
// row comes straight from tok). No atomics, no cross-XCD RMW ping-pong.
// Inner loop byte-identical to R3.
// ---------------------------------------------------------------------------
__global__ __launch_bounds__(256) void gemm_down_mfma(
    const unsigned short* __restrict__ act, const unsigned short* __restrict__ Wdt,
    const float* __restrict__ bd, const int* __restrict__ e_cnt,
    const int* __restrict__ row_token, const float* __restrict__ row_w,
    float* __restrict__ down) {
  int bid = blockIdx.x;
  int g = bid % (E * NT2);
  int mt = bid / (E * NT2);
  int e = g / NT2;
  int n0 = (g % NT2) * 64;
  int cnt = e_cnt[e];
  int m0 = mt * 128;
  if (m0 >= cnt) return;
  int start = e * CAP;
  const unsigned short* Wd = Wdt + (size_t)e * H * I;  // [h][i]
  const float* bias = bd + (size_t)e * H;

  __shared__ short As[2][128 * 64];  // 32 KB
  __shared__ short Bs[2][64 * 64];   // 16 KB
  __shared__ int tok[128];
  __shared__ float wts[128];

  int tid = threadIdx.x;
  if (tid < 128) {
    int m = m0 + tid;
    int mm = (m < cnt) ? m : (cnt - 1);
    tok[tid] = row_token[start + mm];
    wts[tid] = row_w[start + mm];
  }
  __syncthreads();

  int lane = tid & 63;
  int wave = tid >> 6;
  int quad = lane >> 4;
  int lrow = lane & 15;
  int wm = (wave >> 1) * 64;
  int wn = (wave & 1) * 32;

  const unsigned short* gA[4];
  int oA[4];
#pragma unroll
  for (int r = 0; r < 4; r++) {
    int s = (wave * 4 + r) * 64 + lane;
    int row = s >> 3;
    int gg = (s & 7) ^ (row & 7);
    int gm = m0 + row;
    int mm = (gm < cnt) ? gm : (cnt - 1);
    gA[r] = act + (size_t)(start + mm) * I + gg * 8;
    oA[r] = (wave * 4 + r) * 64 * 8;
  }
  const unsigned short* gB[2];
  int oB[2];
#pragma unroll
  for (int r = 0; r < 2; r++) {
    int s = (wave * 2 + r) * 64 + lane;
    int row = s >> 3;
    int gg = (s & 7) ^ (row & 7);
    gB[r] = Wd + (size_t)(n0 + row) * I + gg * 8;
    oB[r] = (wave * 2 + r) * 64 * 8;
  }

  float bdv[2];
#pragma unroll
  for (int tj = 0; tj < 2; tj++) bdv[tj] = bias[n0 + wn + tj * 16 + lrow];

  floatx4 acc[4][2];
#pragma unroll
  for (int i = 0; i < 4; i++)
#pragma unroll
    for (int j = 0; j < 2; j++) acc[i][j] = floatx4{0.f, 0.f, 0.f, 0.f};

  __syncthreads();  // drain; in-loop vmcnt sees only the 6 staging DMAs

#pragma unroll
  for (int r = 0; r < 4; r++) g2l16(gA[r], &As[0][oA[r]]);
#pragma unroll
  for (int r = 0; r < 2; r++) g2l16(gB[r], &Bs[0][oB[r]]);

  constexpr int NK = I / 64;  // 12
  for (int i = 0; i < NK; i++) {
    int cb = i & 1;
    if (i + 1 < NK) {
      int nb = cb ^ 1;
      int k1 = (i + 1) * 64;
#pragma unroll
      for (int r = 0; r < 4; r++) g2l16(gA[r] + k1, &As[nb][oA[r]]);
#pragma unroll
      for (int r = 0; r < 2; r++) g2l16(gB[r] + k1, &Bs[nb][oB[r]]);
      asm volatile("s_waitcnt vmcnt(6)" ::: "memory");
    } else {
      asm volatile("s_waitcnt vmcnt(0)" ::: "memory");
    }
    __builtin_amdgcn_s_barrier();

#pragma unroll
    for (int ks = 0; ks < 2; ks++) {
      int c = ks * 4 + quad;
      short8 a[4], b[2];
#pragma unroll
      for (int ti = 0; ti < 4; ti++) {
        int r = wm + ti * 16 + lrow;
        a[ti] = *(const short8*)(&As[cb][(r * 8 + (c ^ (r & 7))) * 8]);
      }
#pragma unroll
      for (int tj = 0; tj < 2; tj++) {
        int r = wn + tj * 16 + lrow;
        b[tj] = *(const short8*)(&Bs[cb][(r * 8 + (c ^ (r & 7))) * 8]);
      }
#pragma unroll
      for (int ti = 0; ti < 4; ti++)
#pragma unroll
        for (int tj = 0; tj < 2; tj++)
          acc[ti][tj] = __builtin_amdgcn_mfma_f32_16x16x32_bf16(
              a[ti], b[tj], acc[ti][tj], 0, 0, 0);
    }
    __builtin_amdgcn_s_barrier();
  }

#pragma unroll
  for (int ti = 0; ti < 4; ti++) {
#pragma unroll
    for (int tj = 0; tj < 2; tj++) {
      int ncol = n0 + wn + tj * 16 + lrow;
#pragma unroll
      for (int r = 0; r < 4; r++) {
        int ml = wm + ti * 16 + quad * 4 + r;
        int m = m0 + ml;
        if (m < cnt) {
          down[(size_t)tok[ml] * H + ncol] =
              wts[ml] * (acc[ti][tj][r] + bdv[tj]);
        }
      }
    }
  }
}

// ---------------------------------------------------------------------------
// Reduce: out[t][h] = down[t][0][h] + down[t][1][h]. One float4 per thread,
// fully coalesced. 1536 blocks x 256 threads x 1 float4 = T*H floats.
// ---------------------------------------------------------------------------
__global__ __launch_bounds__(256) void reduce_out(
    const float* __restrict__ down, float* __restrict__ out) {
  int i4 = blockIdx.x * 256 + threadIdx.x;  // 0 .. T*H/4-1
  int t = i4 / (H / 4);
  int c = i4 % (H / 4);
  const float4* d0 = (const float4*)(down + (size_t)(2 * t) * H) + c;
  const float4* d1 = (const float4*)(down + (size_t)(2 * t + 1) * H) + c;
  float4 a = *d0, b = *d1;
  float4 r = {a.x + b.x, a.y + b.y, a.z + b.z, a.w + b.w};
  ((float4*)(out + (size_t)t * H))[c] = r;
}

// ---------------------------------------------------------------------------
extern "C" void kernel_launch(void* const* d_in, const int* in_sizes, int n_in,
                              void* d_out, int out_size, void* d_ws,
                              size_t ws_size, hipStream_t stream) {
  const float* x   = (const float*)d_in[0];
  const float* Wr  = (const float*)d_in[1];
  const float* br  = (const float*)d_in[2];
  const float* Wgu = (const float*)d_in[3];
  const float* bgu = (const float*)d_in[4];
  const float* Wd  = (const float*)d_in[5];
  const float* bd  = (const float*)d_in[6];
  float* out = (float*)d_out;

  char* w = (char*)d_ws;
  int* e_cnt = (int*)w;       w += 16 * sizeof(int);
  int* row_token = (int*)w;   w += (size_t)E * CAP * sizeof(int);
  float* row_w = (float*)w;   w += (size_t)E * CAP * sizeof(float);
  unsigned short* xb  = (unsigned short*)w; w += (size_t)T * H * 2;         // 3.1 MB
  unsigned short* Wgt = (unsigned short*)w; w += (size_t)E * TWO_I * H * 2; // 18.9 MB
  unsigned short* Wdt = (unsigned short*)w; w += (size_t)E * H * I * 2;     // 9.4 MB
  unsigned short* act = (unsigned short*)w; w += (size_t)E * CAP * I * 2;   // 25.2 MB
  float* down = (float*)w;    w += (size_t)T * 2 * H * sizeof(float);       // 12.6 MB

  hipMemsetAsync(e_cnt, 0, 16 * sizeof(int), stream);
  pre_router_wgu<<<PRE_BLKS, 256, 0, stream>>>(
      x, Wr, br, Wgu, Wgt, xb, e_cnt, row_token, row_w);
  gemm_gu_wdT<<<K1_BLKS, 256, 0, stream>>>(
      xb, Wgt, bgu, e_cnt, row_token, act, Wd, Wdt);
  gemm_down_mfma<<<G2_BLKS, 256, 0, stream>>>(
      act, Wdt, bd, e_cnt, row_token, row_w, down);
  reduce_out<<<RED_BLKS, 256, 0, stream>>>(down, out);
}